// Round 4
// baseline (14343.764 us; speedup 1.0000x reference)
//
#include <hip/hip_runtime.h>
#include <hip/hip_bf16.h>
#include <cstddef>
#include <cstdint>

#define HDIM 512
#define NNODES 1024
#define NEDGES 16384
#define BATCH 32
#define SEQ 1024
#define DIN 128

#define SLICES 8     // row slices (64 rows each)
#define GROUPS 8     // batch groups
#define GPB 4        // batch elements per group (interleaved in one WG)

#define RLX __ATOMIC_RELAXED
#define AGT __HIP_MEMORY_SCOPE_AGENT

// ---------------------------------------------------------------------------
// Precompute: AWp[d][j] = sum_{e: dst_e=d} Wp[src_e][j]
// ---------------------------------------------------------------------------
__global__ void scatter_awp_kernel(const float* __restrict__ Wp,
                                   const int* __restrict__ src,
                                   const int* __restrict__ dst,
                                   float* __restrict__ AWp) {
    int e = blockIdx.x;        // 16384 blocks
    int c = threadIdx.x;       // 256 threads, 2 cols each
    int s = src[e], d = dst[e];
    atomicAdd(&AWp[d * HDIM + c],        Wp[s * HDIM + c]);
    atomicAdd(&AWp[d * HDIM + 256 + c],  Wp[s * HDIM + 256 + c]);
}

__global__ void scatter_abp_kernel(const float* __restrict__ bp,
                                   const int* __restrict__ src,
                                   const int* __restrict__ dst,
                                   float* __restrict__ Abp) {
    int e = blockIdx.x * blockDim.x + threadIdx.x;
    if (e < NEDGES) atomicAdd(&Abp[dst[e]], bp[src[e]]);
}

// b_eff[i] = bias[i] + bu[i] + sum_d Wu[i][d] * Abp[d]
__global__ void beff_kernel(const float* __restrict__ Wu,
                            const float* __restrict__ Abp,
                            const float* __restrict__ bias,
                            const float* __restrict__ bu,
                            float* __restrict__ beff) {
    int i = threadIdx.x;       // 512 threads, 1 block
    float s = 0.f;
    for (int d = 0; d < NNODES; ++d) s += Wu[i * NNODES + d] * Abp[d];
    beff[i] = bias[i] + bu[i] + s;
}

// ---------------------------------------------------------------------------
// fp32 tiled GEMM: C[m][n] = sum_k A[m][k] * B_(k,n)  (+ optional addend)
//   TB == 0 : B is (K x N) row-major
//   TB == 1 : B is (N x K) row-major (i.e. compute A @ B^T)
// ---------------------------------------------------------------------------
template <int TB>
__global__ __launch_bounds__(256) void gemm64(const float* __restrict__ A,
                                              const float* __restrict__ B,
                                              float* __restrict__ C,
                                              const float* __restrict__ addend,
                                              int M, int N, int K) {
    const int bn = blockIdx.x, bm = blockIdx.y;
    const int tid = threadIdx.x;
    const int tx = tid & 15, ty = tid >> 4;
    const int m0 = bm * 64, n0 = bn * 64;

    __shared__ float As[16][68];   // [kk][m]
    __shared__ float Bs[16][68];   // [kk][n]

    float acc[4][4] = {};

    for (int k0 = 0; k0 < K; k0 += 16) {
        {   // A tile 64x16 -> As[kk][m]
            int kk = tid & 15, m = tid >> 4;
            #pragma unroll
            for (int i = 0; i < 4; ++i)
                As[kk][m + 16 * i] = A[(size_t)(m0 + m + 16 * i) * K + k0 + kk];
        }
        if (TB == 0) {
            int n = tid & 63, kk = tid >> 6;
            #pragma unroll
            for (int i = 0; i < 4; ++i)
                Bs[kk + 4 * i][n] = B[(size_t)(k0 + kk + 4 * i) * N + n0 + n];
        } else {
            int kk = tid & 15, n = tid >> 4;
            #pragma unroll
            for (int i = 0; i < 4; ++i)
                Bs[kk][n + 16 * i] = B[(size_t)(n0 + n + 16 * i) * K + k0 + kk];
        }
        __syncthreads();
        #pragma unroll
        for (int kk = 0; kk < 16; ++kk) {
            float4 a4 = *reinterpret_cast<const float4*>(&As[kk][ty * 4]);
            float4 b4 = *reinterpret_cast<const float4*>(&Bs[kk][tx * 4]);
            float av[4] = {a4.x, a4.y, a4.z, a4.w};
            float bv[4] = {b4.x, b4.y, b4.z, b4.w};
            #pragma unroll
            for (int i = 0; i < 4; ++i)
                #pragma unroll
                for (int j = 0; j < 4; ++j)
                    acc[i][j] += av[i] * bv[j];
        }
        __syncthreads();
    }
    #pragma unroll
    for (int i = 0; i < 4; ++i) {
        int m = m0 + ty * 4 + i;
        #pragma unroll
        for (int j = 0; j < 4; ++j) {
            int n = n0 + tx * 4 + j;
            float v = acc[i][j];
            if (addend) v += addend[(size_t)m * N + n];
            C[(size_t)m * N + n] = v;
        }
    }
}

// ---------------------------------------------------------------------------
// Recurrent scan with G=4 batch-interleaving to hide the IC exchange latency.
// Grid (SLICES=8, GROUPS=8), 512 threads. WG (s,g) owns rows [s*64,s*64+64)
// for batch elements {4g..4g+3}, processed round-robin per step (sub-slots).
// Thread (q=tid>>5, c=tid&31): rows r0=s*64+4q..+3, cols [16c,16c+16).
// h exchanged as (value, step-tag) 8B relaxed agent atomics (proven R3);
// tagged pairs prefetched 2 sub-slots early, tag-miss falls back to re-poll
// (correctness never depends on timing). LDS double-buffered by sub-slot
// parity; one __syncthreads per sub-slot (write(i) is after sync(i-1) which
// is after every thread's read(i-2) in program order).
// ---------------------------------------------------------------------------
__device__ __forceinline__ float wred(float a) {
    a += __shfl_xor(a, 1);
    a += __shfl_xor(a, 2);
    a += __shfl_xor(a, 4);
    a += __shfl_xor(a, 8);
    a += __shfl_xor(a, 16);
    return a;
}

__device__ __forceinline__ void matvec4(const float4 (&w4)[4][4], const float* hq,
                                        int j0, float& a0, float& a1,
                                        float& a2, float& a3) {
    #pragma unroll
    for (int j = 0; j < 4; ++j) {
        float4 h4 = *reinterpret_cast<const float4*>(hq + 4 * ((j + j0) & 3));
        a0 += w4[0][j].x * h4.x + w4[0][j].y * h4.y + w4[0][j].z * h4.z + w4[0][j].w * h4.w;
        a1 += w4[1][j].x * h4.x + w4[1][j].y * h4.y + w4[1][j].z * h4.z + w4[1][j].w * h4.w;
        a2 += w4[2][j].x * h4.x + w4[2][j].y * h4.y + w4[2][j].z * h4.z + w4[2][j].w * h4.w;
        a3 += w4[3][j].x * h4.x + w4[3][j].y * h4.y + w4[3][j].z * h4.z + w4[3][j].w * h4.w;
    }
}

#define SUBSLOT(I, P, U, UB, PI, PT)                                           \
  {                                                                            \
    unsigned long long v = (P);                                                \
    if ((unsigned)(v >> 32) != (unsigned)t) {                                  \
      const unsigned long long* sp = hpair + (size_t)(t & 1) * SLOTS +         \
                                     (size_t)(b0 + (I)) * HDIM + tid;          \
      do {                                                                     \
        v = __hip_atomic_load(sp, RLX, AGT);                                   \
      } while ((unsigned)(v >> 32) != (unsigned)t);                            \
    }                                                                          \
    hs[(I) & 1][tid] = __uint_as_float((unsigned)v);                           \
    __syncthreads();                                                           \
    (P) = __hip_atomic_load(hpair + (size_t)((PT) & 1) * SLOTS +               \
                            (size_t)(b0 + (PI)) * HDIM + tid, RLX, AGT);       \
    float a0 = 0.f, a1 = 0.f, a2 = 0.f, a3 = 0.f;                              \
    matvec4(w4, &hs[(I) & 1][16 * c], j0, a0, a1, a2, a3);                     \
    a0 = wred(a0); a1 = wred(a1); a2 = wred(a2); a3 = wred(a3);                \
    if (c == 0) {                                                              \
      float4 hold = *reinterpret_cast<const float4*>(&hs[(I) & 1][r0]);        \
      float n0 = olk * hold.x + lk * tanhf(a0 + (U).x + be4.x);                \
      float n1 = olk * hold.y + lk * tanhf(a1 + (U).y + be4.y);                \
      float n2 = olk * hold.z + lk * tanhf(a2 + (U).z + be4.z);                \
      float n3 = olk * hold.w + lk * tanhf(a3 + (U).w + be4.w);                \
      unsigned long long* hw = hpair + (size_t)((t + 1) & 1) * SLOTS +         \
                               (size_t)(b0 + (I)) * HDIM + r0;                 \
      unsigned long long tg = ((unsigned long long)(unsigned)(t + 1)) << 32;   \
      __hip_atomic_store(hw + 0, tg | __float_as_uint(n0), RLX, AGT);          \
      __hip_atomic_store(hw + 1, tg | __float_as_uint(n1), RLX, AGT);          \
      __hip_atomic_store(hw + 2, tg | __float_as_uint(n2), RLX, AGT);          \
      __hip_atomic_store(hw + 3, tg | __float_as_uint(n3), RLX, AGT);          \
      *reinterpret_cast<float4*>((UB) + (size_t)t * HDIM + r0) =               \
          make_float4(n0, n1, n2, n3);                                         \
      if (t + 1 < SEQ)                                                         \
        (U) = *reinterpret_cast<const float4*>((UB) + (size_t)(t + 1) * HDIM + r0); \
    }                                                                          \
  }

__launch_bounds__(512, 1)
__global__ void scan_kernel(const float* __restrict__ Weff,
                            const float* __restrict__ beff,
                            float* __restrict__ u_ys,              // (B,S,H) in/out
                            unsigned long long* __restrict__ hpair, // [2][B][H]
                            float leak) {
    const int slice = blockIdx.x;   // 0..7
    const int grp   = blockIdx.y;   // 0..7
    const int tid = threadIdx.x;    // 0..511
    const int q = tid >> 5;         // 0..15 row-quad
    const int c = tid & 31;         // 0..31 col-owner (16 cols)
    const int r0 = slice * 64 + q * 4;
    const int b0 = grp * GPB;
    const int j0 = (c >> 1) & 3;    // chunk stagger: 4-way max on b128 reads
    const size_t SLOTS = (size_t)BATCH * HDIM;

    __shared__ float hs[2][HDIM];

    // per-thread weights: 4 rows x 16 cols, chunk order staggered by j0 so
    // compute pairs w4[r][j] with LDS chunk ((j+j0)&3) -> static indexing.
    float4 w4[4][4];
    #pragma unroll
    for (int r = 0; r < 4; ++r) {
        const float* wr = Weff + (size_t)(r0 + r) * HDIM + 16 * c;
        #pragma unroll
        for (int j = 0; j < 4; ++j)
            w4[r][j] = *reinterpret_cast<const float4*>(wr + 4 * ((j + j0) & 3));
    }
    #pragma unroll
    for (int r = 0; r < 4; ++r)
        #pragma unroll
        for (int j = 0; j < 4; ++j)
            asm volatile("" : "+v"(w4[r][j].x), "+v"(w4[r][j].y),
                              "+v"(w4[r][j].z), "+v"(w4[r][j].w));

    const float4 be4 = *reinterpret_cast<const float4*>(beff + r0);
    const float lk = leak, olk = 1.0f - leak;

    float* ub0 = u_ys + (size_t)(b0 + 0) * SEQ * HDIM;
    float* ub1 = u_ys + (size_t)(b0 + 1) * SEQ * HDIM;
    float* ub2 = u_ys + (size_t)(b0 + 2) * SEQ * HDIM;
    float* ub3 = u_ys + (size_t)(b0 + 3) * SEQ * HDIM;

    // prefetch ring (depth 2): p0 serves sub-slots 0,2; p1 serves 1,3
    unsigned long long p0 = __hip_atomic_load(hpair + (size_t)(b0 + 0) * HDIM + tid, RLX, AGT);
    unsigned long long p1 = __hip_atomic_load(hpair + (size_t)(b0 + 1) * HDIM + tid, RLX, AGT);

    float4 u0 = {}, u1 = {}, u2 = {}, u3 = {};
    if (c == 0) {
        u0 = *reinterpret_cast<const float4*>(ub0 + r0);
        u1 = *reinterpret_cast<const float4*>(ub1 + r0);
        u2 = *reinterpret_cast<const float4*>(ub2 + r0);
        u3 = *reinterpret_cast<const float4*>(ub3 + r0);
    }

    for (int t = 0; t < SEQ; ++t) {
        SUBSLOT(0, p0, u0, ub0, 2, t)
        SUBSLOT(1, p1, u1, ub1, 3, t)
        SUBSLOT(2, p0, u2, ub2, 0, t + 1)
        SUBSLOT(3, p1, u3, ub3, 1, t + 1)
    }
}

// ---------------------------------------------------------------------------
extern "C" void kernel_launch(void* const* d_in, const int* in_sizes, int n_in,
                              void* d_out, int out_size, void* d_ws, size_t ws_size,
                              hipStream_t stream) {
    const float* x      = (const float*)d_in[0];
    const int*   edges  = (const int*)d_in[1];
    const float* W_in0  = (const float*)d_in[2];
    const float* W_res0 = (const float*)d_in[3];
    const float* bias0  = (const float*)d_in[4];
    const float* Wp0    = (const float*)d_in[5];
    const float* bp0    = (const float*)d_in[6];
    const float* Wu0    = (const float*)d_in[7];
    const float* bu0    = (const float*)d_in[8];
    const float* W_in1  = (const float*)d_in[9];
    const float* W_res1 = (const float*)d_in[10];
    const float* bias1  = (const float*)d_in[11];
    const float* Wp1    = (const float*)d_in[12];
    const float* bp1    = (const float*)d_in[13];
    const float* Wu1    = (const float*)d_in[14];
    const float* bu1    = (const float*)d_in[15];

    const int* src = edges;
    const int* dst = edges + NEDGES;
    float* out = (float*)d_out;

    // workspace layout
    char* base = (char*)d_ws;
    float* ws_u  = (float*)base;                 // 32*1024*512*4 = 67,108,864
    char* p = base + (size_t)67108864;
    float* AWp   = (float*)p;  p += 2097152;     // 1024*512*4
    float* Abp   = (float*)p;  p += 4096;        // 1024*4
    float* Weff0 = (float*)p;  p += 1048576;     // 512*512*4
    float* Weff1 = (float*)p;  p += 1048576;
    float* beff0 = (float*)p;  p += 2048;
    float* beff1 = (float*)p;  p += 2048;
    unsigned long long* hpair = (unsigned long long*)p;  // 2*32*512*8 = 262144
    p += 262144;

    // ---- layer 0 effective weights ----
    hipMemsetAsync(AWp, 0, 2097152 + 4096, stream);
    scatter_awp_kernel<<<NEDGES, 256, 0, stream>>>(Wp0, src, dst, AWp);
    scatter_abp_kernel<<<NEDGES / 256, 256, 0, stream>>>(bp0, src, dst, Abp);
    gemm64<0><<<dim3(8, 8), 256, 0, stream>>>(Wu0, AWp, Weff0, W_res0, 512, 512, 1024);
    beff_kernel<<<1, 512, 0, stream>>>(Wu0, Abp, bias0, bu0, beff0);

    // ---- layer 1 effective weights ----
    hipMemsetAsync(AWp, 0, 2097152 + 4096, stream);
    scatter_awp_kernel<<<NEDGES, 256, 0, stream>>>(Wp1, src, dst, AWp);
    scatter_abp_kernel<<<NEDGES / 256, 256, 0, stream>>>(bp1, src, dst, Abp);
    gemm64<0><<<dim3(8, 8), 256, 0, stream>>>(Wu1, AWp, Weff1, W_res1, 512, 512, 1024);
    beff_kernel<<<1, 512, 0, stream>>>(Wu1, Abp, bias1, bu1, beff1);

    // ---- u0 = x @ W_in0^T : (32768 x 128) @ (512 x 128)^T ----
    gemm64<1><<<dim3(512 / 64, 32768 / 64), 256, 0, stream>>>(
        x, W_in0, ws_u, nullptr, BATCH * SEQ, HDIM, DIN);

    // ---- layer 0 scan (in place over ws_u) ----
    hipMemsetAsync(hpair, 0, 262144, stream);   // tags start at 0, h0 = 0
    scan_kernel<<<dim3(SLICES, GROUPS), 512, 0, stream>>>(Weff0, beff0, ws_u, hpair, 0.1f);

    // ---- u1 = ys0 @ W_in1^T : (32768 x 512) @ (512 x 512)^T -> d_out ----
    gemm64<1><<<dim3(512 / 64, 32768 / 64), 256, 0, stream>>>(
        ws_u, W_in1, out, nullptr, BATCH * SEQ, HDIM, HDIM);

    // ---- layer 1 scan (in place over d_out) ----
    hipMemsetAsync(hpair, 0, 262144, stream);
    scan_kernel<<<dim3(SLICES, GROUPS), 512, 0, stream>>>(Weff1, beff1, out, hpair, 0.15f);
}

// Round 5
// 4629.322 us; speedup vs baseline: 3.0985x; 3.0985x over previous
//
#include <hip/hip_runtime.h>
#include <hip/hip_bf16.h>
#include <cstddef>
#include <cstdint>

#define HDIM 512
#define NNODES 1024
#define NEDGES 16384
#define BATCH 32
#define SEQ 1024
#define DIN 128
#define SLICES 8

#define RLX __ATOMIC_RELAXED
#define AGT __HIP_MEMORY_SCOPE_AGENT

// ---------------------------------------------------------------------------
// Precompute: AWp[d][j] = sum_{e: dst_e=d} Wp[src_e][j]
// ---------------------------------------------------------------------------
__global__ void scatter_awp_kernel(const float* __restrict__ Wp,
                                   const int* __restrict__ src,
                                   const int* __restrict__ dst,
                                   float* __restrict__ AWp) {
    int e = blockIdx.x;        // 16384 blocks
    int c = threadIdx.x;       // 256 threads, 2 cols each
    int s = src[e], d = dst[e];
    atomicAdd(&AWp[d * HDIM + c],        Wp[s * HDIM + c]);
    atomicAdd(&AWp[d * HDIM + 256 + c],  Wp[s * HDIM + 256 + c]);
}

__global__ void scatter_abp_kernel(const float* __restrict__ bp,
                                   const int* __restrict__ src,
                                   const int* __restrict__ dst,
                                   float* __restrict__ Abp) {
    int e = blockIdx.x * blockDim.x + threadIdx.x;
    if (e < NEDGES) atomicAdd(&Abp[dst[e]], bp[src[e]]);
}

// b_eff[i] = bias[i] + bu[i] + sum_d Wu[i][d] * Abp[d]
__global__ void beff_kernel(const float* __restrict__ Wu,
                            const float* __restrict__ Abp,
                            const float* __restrict__ bias,
                            const float* __restrict__ bu,
                            float* __restrict__ beff) {
    int i = threadIdx.x;       // 512 threads, 1 block
    float s = 0.f;
    for (int d = 0; d < NNODES; ++d) s += Wu[i * NNODES + d] * Abp[d];
    beff[i] = bias[i] + bu[i] + s;
}

// ---------------------------------------------------------------------------
// fp32 tiled GEMM: C[m][n] = sum_k A[m][k] * B_(k,n)  (+ optional addend)
//   TB == 0 : B is (K x N) row-major
//   TB == 1 : B is (N x K) row-major (i.e. compute A @ B^T)
// ---------------------------------------------------------------------------
template <int TB>
__global__ __launch_bounds__(256) void gemm64(const float* __restrict__ A,
                                              const float* __restrict__ B,
                                              float* __restrict__ C,
                                              const float* __restrict__ addend,
                                              int M, int N, int K) {
    const int bn = blockIdx.x, bm = blockIdx.y;
    const int tid = threadIdx.x;
    const int tx = tid & 15, ty = tid >> 4;
    const int m0 = bm * 64, n0 = bn * 64;

    __shared__ float As[16][68];   // [kk][m]
    __shared__ float Bs[16][68];   // [kk][n]

    float acc[4][4] = {};

    for (int k0 = 0; k0 < K; k0 += 16) {
        {   // A tile 64x16 -> As[kk][m]
            int kk = tid & 15, m = tid >> 4;
            #pragma unroll
            for (int i = 0; i < 4; ++i)
                As[kk][m + 16 * i] = A[(size_t)(m0 + m + 16 * i) * K + k0 + kk];
        }
        if (TB == 0) {
            int n = tid & 63, kk = tid >> 6;
            #pragma unroll
            for (int i = 0; i < 4; ++i)
                Bs[kk + 4 * i][n] = B[(size_t)(k0 + kk + 4 * i) * N + n0 + n];
        } else {
            int kk = tid & 15, n = tid >> 4;
            #pragma unroll
            for (int i = 0; i < 4; ++i)
                Bs[kk][n + 16 * i] = B[(size_t)(n0 + n + 16 * i) * K + k0 + kk];
        }
        __syncthreads();
        #pragma unroll
        for (int kk = 0; kk < 16; ++kk) {
            float4 a4 = *reinterpret_cast<const float4*>(&As[kk][ty * 4]);
            float4 b4 = *reinterpret_cast<const float4*>(&Bs[kk][tx * 4]);
            float av[4] = {a4.x, a4.y, a4.z, a4.w};
            float bv[4] = {b4.x, b4.y, b4.z, b4.w};
            #pragma unroll
            for (int i = 0; i < 4; ++i)
                #pragma unroll
                for (int j = 0; j < 4; ++j)
                    acc[i][j] += av[i] * bv[j];
        }
        __syncthreads();
    }
    #pragma unroll
    for (int i = 0; i < 4; ++i) {
        int m = m0 + ty * 4 + i;
        #pragma unroll
        for (int j = 0; j < 4; ++j) {
            int n = n0 + tx * 4 + j;
            float v = acc[i][j];
            if (addend) v += addend[(size_t)m * N + n];
            C[(size_t)m * N + n] = v;
        }
    }
}

// ---------------------------------------------------------------------------
// DPP half-wave (32-lane) sum. After 5 stages, lane31 holds sum of lanes
// 0-31 and lane63 holds sum of lanes 32-63 (VALU pipe; no DS traffic).
// row_shr:k = 0x110|k ; row_bcast:15 = 0x142 (row_mask 0xa -> rows 1,3 only,
// so halves never mix).
// ---------------------------------------------------------------------------
template <int CTRL, int RMASK, bool BC>
__device__ __forceinline__ float dpp_add(float x) {
    int t = __builtin_amdgcn_update_dpp(0, __float_as_int(x), CTRL, RMASK, 0xf, BC);
    return x + __int_as_float(t);
}

__device__ __forceinline__ float reduce32(float x) {
    x = dpp_add<0x111, 0xf, true>(x);   // row_shr:1
    x = dpp_add<0x112, 0xf, true>(x);   // row_shr:2
    x = dpp_add<0x114, 0xf, true>(x);   // row_shr:4
    x = dpp_add<0x118, 0xf, true>(x);   // row_shr:8
    x = dpp_add<0x142, 0xa, false>(x);  // row_bcast:15 into rows 1,3
    return x;
}

__device__ __forceinline__ float fast_tanh(float x) {
    float e = __expf(2.0f * x);         // v_exp_f32 path; exact at saturation
    return 1.0f - 2.0f / (e + 1.0f);
}

// ---------------------------------------------------------------------------
// Recurrent scan. Grid (8 slices, 32 batch), 512 threads, 1 batch per WG
// (R3 skeleton: tag-pair exchange, parity double-buffer, 1 barrier/step).
// Thread (hw=tid>>5, c=tid&31): rows rowbase=slice*64+4*hw..+4, cols = four
// float4 chunks at indices {c+32k} (strided -> bank-conflict-free b128).
// Each h chunk feeds 4 rows (LDS instr / 4 vs R3). Half-wave DPP reduce puts
// row sums exactly at store lanes (c==31). h_old kept in the store lane's
// registers. Weights pinned in VGPRs with an in-loop asm identity.
// ---------------------------------------------------------------------------
__launch_bounds__(512, 2)
__global__ void scan_kernel(const float* __restrict__ Weff,
                            const float* __restrict__ beff,
                            float* __restrict__ u_ys,               // (B,S,H) in/out
                            unsigned long long* __restrict__ hpair, // [2][B][H]
                            float leak) {
    const int slice = blockIdx.x;   // 0..7
    const int b = blockIdx.y;       // 0..31
    const int tid = threadIdx.x;    // 0..511
    const int c = tid & 31;         // col-owner within half-wave
    const int hw = tid >> 5;        // half-wave 0..15
    const int rowbase = slice * 64 + hw * 4;
    const bool storer = (c == 31);
    const size_t SLOTS = (size_t)BATCH * HDIM;

    __shared__ float hs[2][HDIM];

    // weights: 4 rows x 4 strided float4 chunks
    float4 w[4][4];
    #pragma unroll
    for (int m = 0; m < 4; ++m)
        #pragma unroll
        for (int k = 0; k < 4; ++k)
            w[m][k] = *reinterpret_cast<const float4*>(
                Weff + (size_t)(rowbase + m) * HDIM + 4 * (c + 32 * k));

    float4 be4 = make_float4(0.f, 0.f, 0.f, 0.f);
    if (storer) be4 = *reinterpret_cast<const float4*>(beff + rowbase);
    const float lk = leak, olk = 1.0f - leak;
    float* ub = u_ys + (size_t)b * SEQ * HDIM;
    unsigned long long* hb = hpair + (size_t)b * HDIM;
    float4 hold = make_float4(0.f, 0.f, 0.f, 0.f);  // h(0) = 0

    for (int t = 0; t < SEQ; ++t) {
        // re-pin weights every iteration: reloading them before this opaque
        // asm would cost as much as keeping them live -> allocator keeps them.
        #pragma unroll
        for (int m = 0; m < 4; ++m)
            asm volatile("" : "+v"(w[m][0].x), "+v"(w[m][0].y), "+v"(w[m][0].z), "+v"(w[m][0].w),
                              "+v"(w[m][1].x), "+v"(w[m][1].y), "+v"(w[m][1].z), "+v"(w[m][1].w),
                              "+v"(w[m][2].x), "+v"(w[m][2].y), "+v"(w[m][2].z), "+v"(w[m][2].w),
                              "+v"(w[m][3].x), "+v"(w[m][3].y), "+v"(w[m][3].z), "+v"(w[m][3].w));

        // u prefetch (store lanes only) -- latency hides under the poll
        float4 u4 = make_float4(0.f, 0.f, 0.f, 0.f);
        if (storer) u4 = *reinterpret_cast<const float4*>(ub + (size_t)t * HDIM + rowbase);

        // poll own slot for tag t (cache-bypassing relaxed agent atomic)
        const unsigned long long* sp = hb + (size_t)(t & 1) * SLOTS + tid;
        unsigned long long v;
        do {
            v = __hip_atomic_load(sp, RLX, AGT);
        } while ((unsigned)(v >> 32) != (unsigned)t);
        hs[t & 1][tid] = __uint_as_float((unsigned)v);
        __syncthreads();

        // 4 rows x 16 cols of FMA; each b128 read feeds 4 rows
        float a0 = 0.f, a1 = 0.f, a2 = 0.f, a3 = 0.f;
        const float* hst = hs[t & 1];
        #pragma unroll
        for (int k = 0; k < 4; ++k) {
            float4 h4 = *reinterpret_cast<const float4*>(hst + 4 * (c + 32 * k));
            a0 += w[0][k].x * h4.x + w[0][k].y * h4.y + w[0][k].z * h4.z + w[0][k].w * h4.w;
            a1 += w[1][k].x * h4.x + w[1][k].y * h4.y + w[1][k].z * h4.z + w[1][k].w * h4.w;
            a2 += w[2][k].x * h4.x + w[2][k].y * h4.y + w[2][k].z * h4.z + w[2][k].w * h4.w;
            a3 += w[3][k].x * h4.x + w[3][k].y * h4.y + w[3][k].z * h4.z + w[3][k].w * h4.w;
        }
        a0 = reduce32(a0);
        a1 = reduce32(a1);
        a2 = reduce32(a2);
        a3 = reduce32(a3);

        if (storer) {   // lanes 31/63: row sums for this half-wave's 4 rows
            float n0 = olk * hold.x + lk * fast_tanh(a0 + u4.x + be4.x);
            float n1 = olk * hold.y + lk * fast_tanh(a1 + u4.y + be4.y);
            float n2 = olk * hold.z + lk * fast_tanh(a2 + u4.z + be4.z);
            float n3 = olk * hold.w + lk * fast_tanh(a3 + u4.w + be4.w);
            hold = make_float4(n0, n1, n2, n3);
            unsigned long long tg = ((unsigned long long)(unsigned)(t + 1)) << 32;
            unsigned long long* hw_p = hb + (size_t)((t + 1) & 1) * SLOTS + rowbase;
            __hip_atomic_store(hw_p + 0, tg | __float_as_uint(n0), RLX, AGT);
            __hip_atomic_store(hw_p + 1, tg | __float_as_uint(n1), RLX, AGT);
            __hip_atomic_store(hw_p + 2, tg | __float_as_uint(n2), RLX, AGT);
            __hip_atomic_store(hw_p + 3, tg | __float_as_uint(n3), RLX, AGT);
            *reinterpret_cast<float4*>(ub + (size_t)t * HDIM + rowbase) =
                make_float4(n0, n1, n2, n3);   // ys, in place over u
        }
    }
}

// ---------------------------------------------------------------------------
extern "C" void kernel_launch(void* const* d_in, const int* in_sizes, int n_in,
                              void* d_out, int out_size, void* d_ws, size_t ws_size,
                              hipStream_t stream) {
    const float* x      = (const float*)d_in[0];
    const int*   edges  = (const int*)d_in[1];
    const float* W_in0  = (const float*)d_in[2];
    const float* W_res0 = (const float*)d_in[3];
    const float* bias0  = (const float*)d_in[4];
    const float* Wp0    = (const float*)d_in[5];
    const float* bp0    = (const float*)d_in[6];
    const float* Wu0    = (const float*)d_in[7];
    const float* bu0    = (const float*)d_in[8];
    const float* W_in1  = (const float*)d_in[9];
    const float* W_res1 = (const float*)d_in[10];
    const float* bias1  = (const float*)d_in[11];
    const float* Wp1    = (const float*)d_in[12];
    const float* bp1    = (const float*)d_in[13];
    const float* Wu1    = (const float*)d_in[14];
    const float* bu1    = (const float*)d_in[15];

    const int* src = edges;
    const int* dst = edges + NEDGES;
    float* out = (float*)d_out;

    // workspace layout
    char* base = (char*)d_ws;
    float* ws_u  = (float*)base;                 // 32*1024*512*4 = 67,108,864
    char* p = base + (size_t)67108864;
    float* AWp   = (float*)p;  p += 2097152;     // 1024*512*4
    float* Abp   = (float*)p;  p += 4096;        // 1024*4
    float* Weff0 = (float*)p;  p += 1048576;     // 512*512*4
    float* Weff1 = (float*)p;  p += 1048576;
    float* beff0 = (float*)p;  p += 2048;
    float* beff1 = (float*)p;  p += 2048;
    unsigned long long* hpair = (unsigned long long*)p;  // 2*32*512*8 = 262144
    p += 262144;

    // ---- layer 0 effective weights ----
    hipMemsetAsync(AWp, 0, 2097152 + 4096, stream);
    scatter_awp_kernel<<<NEDGES, 256, 0, stream>>>(Wp0, src, dst, AWp);
    scatter_abp_kernel<<<NEDGES / 256, 256, 0, stream>>>(bp0, src, dst, Abp);
    gemm64<0><<<dim3(8, 8), 256, 0, stream>>>(Wu0, AWp, Weff0, W_res0, 512, 512, 1024);
    beff_kernel<<<1, 512, 0, stream>>>(Wu0, Abp, bias0, bu0, beff0);

    // ---- layer 1 effective weights ----
    hipMemsetAsync(AWp, 0, 2097152 + 4096, stream);
    scatter_awp_kernel<<<NEDGES, 256, 0, stream>>>(Wp1, src, dst, AWp);
    scatter_abp_kernel<<<NEDGES / 256, 256, 0, stream>>>(bp1, src, dst, Abp);
    gemm64<0><<<dim3(8, 8), 256, 0, stream>>>(Wu1, AWp, Weff1, W_res1, 512, 512, 1024);
    beff_kernel<<<1, 512, 0, stream>>>(Wu1, Abp, bias1, bu1, beff1);

    // ---- u0 = x @ W_in0^T : (32768 x 128) @ (512 x 128)^T ----
    gemm64<1><<<dim3(512 / 64, 32768 / 64), 256, 0, stream>>>(
        x, W_in0, ws_u, nullptr, BATCH * SEQ, HDIM, DIN);

    // ---- layer 0 scan (in place over ws_u) ----
    hipMemsetAsync(hpair, 0, 262144, stream);   // tags 0, h0 = 0
    scan_kernel<<<dim3(SLICES, BATCH), 512, 0, stream>>>(Weff0, beff0, ws_u, hpair, 0.1f);

    // ---- u1 = ys0 @ W_in1^T : (32768 x 512) @ (512 x 512)^T -> d_out ----
    gemm64<1><<<dim3(512 / 64, 32768 / 64), 256, 0, stream>>>(
        ws_u, W_in1, out, nullptr, BATCH * SEQ, HDIM, HDIM);

    // ---- layer 1 scan (in place over d_out) ----
    hipMemsetAsync(hpair, 0, 262144, stream);
    scan_kernel<<<dim3(SLICES, BATCH), 512, 0, stream>>>(Weff1, beff1, out, hpair, 0.15f);
}